// Round 6
// baseline (166.826 us; speedup 1.0000x reference)
//
#include <hip/hip_runtime.h>

#define BB 512
#define SS 512
#define TT 64
#define TSTRIDE 66   // transitions is (66,66)

typedef _Float16 h2 __attribute__((ext_vector_type(2)));

static __device__ __forceinline__ float first_lane(float v) {
    return __int_as_float(__builtin_amdgcn_readfirstlane(__float_as_int(v)));
}
static __device__ __forceinline__ unsigned pk_f16(float a, float b) {
    return __builtin_bit_cast(unsigned, __builtin_amdgcn_cvt_pkrtz(a, b));
}
static __device__ __forceinline__ h2 as_h2(unsigned u) {
    return __builtin_bit_cast(h2, u);
}
#define FDOT2(a, b, c) __builtin_amdgcn_fdot2((a), (b), (c), false)

// One wave per batch, lane j owns score[j].
// R1-R5 lesson: all variants ran ~975 cy/step regardless of where E lived
// (scratch / remat / LDS) => every step exposed one full HBM latency because
// some per-step vmcnt traffic (scratch, remat loads, mask load, asm clobber)
// drained the emission prefetch queue. R6: the ONLY in-loop memory op is the
// emission load, depth-8 register ring, manually unrolled x8 so all ring
// indices are static. Mask -> precomputed len (pure SALU in loop). E hoisted
// to 8 named uint4 (32 VGPRs) behind a __syncthreads.
__global__ __launch_bounds__(64)
__attribute__((amdgpu_waves_per_eu(1, 1)))
void crf_fused_kernel(
    const float* __restrict__ emissions,   // [B,S,T]
    const int*   __restrict__ tags,        // [B,S]
    const float* __restrict__ mask,        // [B,S]
    const float* __restrict__ trans,       // [66,66]
    float* __restrict__ diff_out)          // [B] = logZ - gold
{
    __shared__ uint4 EQ[8][64];   // 8 KB: E[i][j]=exp(tt[i][j]) f16-packed

    const int b = blockIdx.x;
    const int j = threadIdx.x;   // 0..63
    const bool odd = (j & 1) != 0;

    const float* em = emissions + (size_t)b * SS * TT;
    const float* mk = mask + (size_t)b * SS;

    #pragma unroll
    for (int q = 0; q < 8; ++q) {
        float x0 = __expf(trans[(8 * q + 0) * TSTRIDE + j]);
        float x1 = __expf(trans[(8 * q + 1) * TSTRIDE + j]);
        float x2 = __expf(trans[(8 * q + 2) * TSTRIDE + j]);
        float x3 = __expf(trans[(8 * q + 3) * TSTRIDE + j]);
        float x4 = __expf(trans[(8 * q + 4) * TSTRIDE + j]);
        float x5 = __expf(trans[(8 * q + 5) * TSTRIDE + j]);
        float x6 = __expf(trans[(8 * q + 6) * TSTRIDE + j]);
        float x7 = __expf(trans[(8 * q + 7) * TSTRIDE + j]);
        uint4 v;
        v.x = pk_f16(x0, x1);
        v.y = pk_f16(x2, x3);
        v.z = pk_f16(x4, x5);
        v.w = pk_f16(x6, x7);
        EQ[q][j] = v;
    }
    __syncthreads();

    // Hoist E to registers (32 VGPRs); barrier above blocks rematerialization.
    const uint4 c0 = EQ[0][j], c1 = EQ[1][j], c2 = EQ[2][j], c3 = EQ[3][j];
    const uint4 c4 = EQ[4][j], c5 = EQ[5][j], c6 = EQ[6][j], c7 = EQ[7][j];

    // len = sum(mask row) — mask is a 0/1 length-prefix
    float msum = 0.f;
    #pragma unroll
    for (int t = 0; t < 8; ++t) msum += mk[j + 64 * t];
    #pragma unroll
    for (int off = 32; off; off >>= 1) msum += __shfl_xor(msum, off);
    const int len = (int)(first_lane(msum) + 0.5f);   // in [256,512], so mask[0]=1

    // score0[j] = em[0,j] + trans[j, start=64]   (mask[0] == 1 always)
    float score = em[j] + trans[j * TSTRIDE + TT];

    // chunk q word w holds E rows {8q+2w, 8q+2w+1}; p-pair via readlane(8q+2w)
#define DOTC(C, Q) \
    a0 = FDOT2(as_h2((unsigned)__builtin_amdgcn_readlane(pki, 8*(Q)+0)), as_h2((C).x), a0); \
    a1 = FDOT2(as_h2((unsigned)__builtin_amdgcn_readlane(pki, 8*(Q)+2)), as_h2((C).y), a1); \
    a2 = FDOT2(as_h2((unsigned)__builtin_amdgcn_readlane(pki, 8*(Q)+4)), as_h2((C).z), a2); \
    a3 = FDOT2(as_h2((unsigned)__builtin_amdgcn_readlane(pki, 8*(Q)+6)), as_h2((C).w), a3);

#define STEP(EMIT, SVAL) do { \
        float m0c = first_lane(score) + 4.0f; \
        float p   = __expf(score - m0c); \
        float pn  = __int_as_float(__builtin_amdgcn_mov_dpp( \
                        __float_as_int(p), 0xB1, 0xF, 0xF, true)); \
        float lo_ = odd ? pn : p; \
        float hi_ = odd ? p  : pn; \
        int   pki = (int)pk_f16(lo_, hi_); \
        float a0 = 0.f, a1 = 0.f, a2 = 0.f, a3 = 0.f; \
        DOTC(c0, 0) DOTC(c1, 1) DOTC(c2, 2) DOTC(c3, 3) \
        DOTC(c4, 4) DOTC(c5, 5) DOTC(c6, 6) DOTC(c7, 7) \
        float ee = ((SVAL) < len) ? (EMIT) : 0.0f; \
        score = m0c + __logf((a0 + a1) + (a2 + a3)) + ee; \
    } while (0)

    // emission ring, depth 8 (rows 1..8)
    float r0 = em[1 * TT + j], r1 = em[2 * TT + j];
    float r2 = em[3 * TT + j], r3 = em[4 * TT + j];
    float r4 = em[5 * TT + j], r5 = em[6 * TT + j];
    float r6 = em[7 * TT + j], r7 = em[8 * TT + j];

    const float* pe = em + 9 * TT + j;   // next row to load
    int scur = 1;
    // main: 62 iters x 8 steps = steps 1..496; loads rows 9..504
    for (int it = 0; it < 62; ++it) {
        float n0 = pe[0],   n1 = pe[64],  n2 = pe[128], n3 = pe[192];
        float n4 = pe[256], n5 = pe[320], n6 = pe[384], n7 = pe[448];
        pe += 512;
        STEP(r0, scur + 0); STEP(r1, scur + 1);
        STEP(r2, scur + 2); STEP(r3, scur + 3);
        STEP(r4, scur + 4); STEP(r5, scur + 5);
        STEP(r6, scur + 6); STEP(r7, scur + 7);
        scur += 8;
        r0 = n0; r1 = n1; r2 = n2; r3 = n3;
        r4 = n4; r5 = n5; r6 = n6; r7 = n7;
    }
    // epilogue: ring = rows 497..504; load rows 505..511, then 15 steps
    {
        float t0 = pe[0],   t1 = pe[64],  t2 = pe[128], t3 = pe[192];
        float t4 = pe[256], t5 = pe[320], t6 = pe[384];
        STEP(r0, 497); STEP(r1, 498); STEP(r2, 499); STEP(r3, 500);
        STEP(r4, 501); STEP(r5, 502); STEP(r6, 503); STEP(r7, 504);
        STEP(t0, 505); STEP(t1, 506); STEP(t2, 507); STEP(t3, 508);
        STEP(t4, 509); STEP(t5, 510); STEP(t6, 511);
    }
#undef STEP
#undef DOTC

    // + trans[stop=65, j], exact wave logsumexp (f32)
    score += trans[65 * TSTRIDE + j];
    float m = score;
    #pragma unroll
    for (int off = 32; off; off >>= 1) m = fmaxf(m, __shfl_xor(m, off));
    float e = __expf(score - m);
    #pragma unroll
    for (int off = 32; off; off >>= 1) e += __shfl_xor(e, off);
    float zres = m + __logf(e);   // valid in lane 0

    // ---- gold path (mask -> s < len) ----
    const int* tg = tags + (size_t)b * SS;
    float acc = 0.f;
    for (int s = j; s < SS; s += 64) {
        if (s < len) {
            if (s > 0) {
                int curr = tg[s], prev = tg[s - 1];
                acc += trans[curr * TSTRIDE + prev] + em[s * TT + curr];
            } else {
                int t0_ = tg[0];
                acc += em[t0_] + trans[t0_ * TSTRIDE + TT];
            }
        }
    }
    #pragma unroll
    for (int off = 32; off; off >>= 1) acc += __shfl_xor(acc, off);
    if (j == 0) {
        int last = tg[len - 1];
        acc += trans[65 * TSTRIDE + last];
        diff_out[b] = zres - acc;
    }
}

__global__ __launch_bounds__(256) void crf_final_kernel(
    const float* __restrict__ diff,
    float* __restrict__ out)
{
    __shared__ float sdata[4];
    int t = threadIdx.x;
    float v = 0.f;
    for (int i = t; i < BB; i += 256) v += diff[i];
    #pragma unroll
    for (int off = 32; off; off >>= 1) v += __shfl_xor(v, off);
    if ((t & 63) == 0) sdata[t >> 6] = v;
    __syncthreads();
    if (t == 0) out[0] = (sdata[0] + sdata[1] + sdata[2] + sdata[3]) * (1.0f / BB);
}

extern "C" void kernel_launch(void* const* d_in, const int* in_sizes, int n_in,
                              void* d_out, int out_size, void* d_ws, size_t ws_size,
                              hipStream_t stream) {
    const float* emissions = (const float*)d_in[0];
    const int*   tags      = (const int*)d_in[1];
    const float* mask      = (const float*)d_in[2];
    const float* trans     = (const float*)d_in[3];
    float* out  = (float*)d_out;
    float* diff = (float*)d_ws;

    crf_fused_kernel<<<BB, 64, 0, stream>>>(emissions, tags, mask, trans, diff);
    crf_final_kernel<<<1, 256, 0, stream>>>(diff, out);
}

// Round 7
// 104.750 us; speedup vs baseline: 1.5926x; 1.5926x over previous
//
#include <hip/hip_runtime.h>

#define BB 512
#define SS 512
#define TT 64
#define TSTRIDE 66   // transitions is (66,66)

typedef _Float16 h2 __attribute__((ext_vector_type(2)));

static __device__ __forceinline__ float first_lane(float v) {
    return __int_as_float(__builtin_amdgcn_readfirstlane(__float_as_int(v)));
}
static __device__ __forceinline__ unsigned pk_f16(float a, float b) {
    return __builtin_bit_cast(unsigned, __builtin_amdgcn_cvt_pkrtz(a, b));
}
static __device__ __forceinline__ h2 as_h2(unsigned u) {
    return __builtin_bit_cast(h2, u);
}
#define FDOT2(a, b, c) __builtin_amdgcn_fdot2((a), (b), (c), false)

// One wave per batch, lane j owns score[j].
// R6 lesson: per-step cost stuck at ~775cy with vmcnt clean => stall was the
// 32x (v_readlane -> SGPR -> v_dot2) hazard chain. R7: broadcast p via LDS
// instead: lane j ds_write_b16's p_j, all lanes ds_read_b128 the whole
// p-vector back (lane-uniform address = broadcast, conflict-free). Dots are
// VGPR-only; readlane/DPP/pack all gone.
__global__ __launch_bounds__(64)
__attribute__((amdgpu_waves_per_eu(1, 1)))
void crf_fused_kernel(
    const float* __restrict__ emissions,   // [B,S,T]
    const int*   __restrict__ tags,        // [B,S]
    const float* __restrict__ mask,        // [B,S]
    const float* __restrict__ trans,       // [66,66]
    float* __restrict__ diff_out)          // [B] = logZ - gold
{
    __shared__ uint4 EQ[8][64];            // 8 KB: E[i][j]=exp(tt[i][j]) f16
    __shared__ unsigned short PL[64];      // p broadcast buffer (f16)

    const int b = blockIdx.x;
    const int j = threadIdx.x;   // 0..63

    const float* em = emissions + (size_t)b * SS * TT;
    const float* mk = mask + (size_t)b * SS;

    #pragma unroll
    for (int q = 0; q < 8; ++q) {
        float x0 = __expf(trans[(8 * q + 0) * TSTRIDE + j]);
        float x1 = __expf(trans[(8 * q + 1) * TSTRIDE + j]);
        float x2 = __expf(trans[(8 * q + 2) * TSTRIDE + j]);
        float x3 = __expf(trans[(8 * q + 3) * TSTRIDE + j]);
        float x4 = __expf(trans[(8 * q + 4) * TSTRIDE + j]);
        float x5 = __expf(trans[(8 * q + 5) * TSTRIDE + j]);
        float x6 = __expf(trans[(8 * q + 6) * TSTRIDE + j]);
        float x7 = __expf(trans[(8 * q + 7) * TSTRIDE + j]);
        uint4 v;
        v.x = pk_f16(x0, x1);
        v.y = pk_f16(x2, x3);
        v.z = pk_f16(x4, x5);
        v.w = pk_f16(x6, x7);
        EQ[q][j] = v;
    }
    __syncthreads();

    // Hoist E to registers (32 VGPRs); barrier above blocks rematerialization.
    const uint4 c0 = EQ[0][j], c1 = EQ[1][j], c2 = EQ[2][j], c3 = EQ[3][j];
    const uint4 c4 = EQ[4][j], c5 = EQ[5][j], c6 = EQ[6][j], c7 = EQ[7][j];

    const uint4* PV = (const uint4*)PL;    // lane-uniform broadcast reads

    // len = sum(mask row) — mask is a 0/1 length-prefix
    float msum = 0.f;
    #pragma unroll
    for (int t = 0; t < 8; ++t) msum += mk[j + 64 * t];
    #pragma unroll
    for (int off = 32; off; off >>= 1) msum += __shfl_xor(msum, off);
    const int len = (int)(first_lane(msum) + 0.5f);   // in [256,512]

    // score0[j] = em[0,j] + trans[j, start=64]   (mask[0] == 1 always)
    float score = em[j] + trans[j * TSTRIDE + TT];

    // word w of chunk q pairs rows {8q+2w, 8q+2w+1}; PV[q] words match.
#define DOTQ(D, C) \
    a0 = FDOT2(as_h2((D).x), as_h2((C).x), a0); \
    a1 = FDOT2(as_h2((D).y), as_h2((C).y), a1); \
    a2 = FDOT2(as_h2((D).z), as_h2((C).z), a2); \
    a3 = FDOT2(as_h2((D).w), as_h2((C).w), a3);

#define STEP(EMIT, SVAL) do { \
        float m0c = first_lane(score) + 4.0f; \
        float p   = __expf(score - m0c); \
        PL[j] = __builtin_bit_cast(unsigned short, (_Float16)p); \
        uint4 d0 = PV[0], d1 = PV[1], d2 = PV[2], d3 = PV[3]; \
        uint4 d4 = PV[4], d5 = PV[5], d6 = PV[6], d7 = PV[7]; \
        float a0 = 0.f, a1 = 0.f, a2 = 0.f, a3 = 0.f; \
        DOTQ(d0, c0) DOTQ(d1, c1) DOTQ(d2, c2) DOTQ(d3, c3) \
        DOTQ(d4, c4) DOTQ(d5, c5) DOTQ(d6, c6) DOTQ(d7, c7) \
        float ee = ((SVAL) < len) ? (EMIT) : 0.0f; \
        score = m0c + __logf((a0 + a1) + (a2 + a3)) + ee; \
    } while (0)

    // emission ring, depth 8 (rows 1..8)
    float r0 = em[1 * TT + j], r1 = em[2 * TT + j];
    float r2 = em[3 * TT + j], r3 = em[4 * TT + j];
    float r4 = em[5 * TT + j], r5 = em[6 * TT + j];
    float r6 = em[7 * TT + j], r7 = em[8 * TT + j];

    const float* pe = em + 9 * TT + j;   // next row to load
    int scur = 1;
    // main: 62 iters x 8 steps = steps 1..496; loads rows 9..504
    for (int it = 0; it < 62; ++it) {
        float n0 = pe[0],   n1 = pe[64],  n2 = pe[128], n3 = pe[192];
        float n4 = pe[256], n5 = pe[320], n6 = pe[384], n7 = pe[448];
        pe += 512;
        STEP(r0, scur + 0); STEP(r1, scur + 1);
        STEP(r2, scur + 2); STEP(r3, scur + 3);
        STEP(r4, scur + 4); STEP(r5, scur + 5);
        STEP(r6, scur + 6); STEP(r7, scur + 7);
        scur += 8;
        r0 = n0; r1 = n1; r2 = n2; r3 = n3;
        r4 = n4; r5 = n5; r6 = n6; r7 = n7;
    }
    // epilogue: ring = rows 497..504; load rows 505..511, then 15 steps
    {
        float t0 = pe[0],   t1 = pe[64],  t2 = pe[128], t3 = pe[192];
        float t4 = pe[256], t5 = pe[320], t6 = pe[384];
        STEP(r0, 497); STEP(r1, 498); STEP(r2, 499); STEP(r3, 500);
        STEP(r4, 501); STEP(r5, 502); STEP(r6, 503); STEP(r7, 504);
        STEP(t0, 505); STEP(t1, 506); STEP(t2, 507); STEP(t3, 508);
        STEP(t4, 509); STEP(t5, 510); STEP(t6, 511);
    }
#undef STEP
#undef DOTQ

    // + trans[stop=65, j], exact wave logsumexp (f32)
    score += trans[65 * TSTRIDE + j];
    float m = score;
    #pragma unroll
    for (int off = 32; off; off >>= 1) m = fmaxf(m, __shfl_xor(m, off));
    float e = __expf(score - m);
    #pragma unroll
    for (int off = 32; off; off >>= 1) e += __shfl_xor(e, off);
    float zres = m + __logf(e);   // valid in lane 0

    // ---- gold path (mask -> s < len) ----
    const int* tg = tags + (size_t)b * SS;
    float acc = 0.f;
    for (int s = j; s < SS; s += 64) {
        if (s < len) {
            if (s > 0) {
                int curr = tg[s], prev = tg[s - 1];
                acc += trans[curr * TSTRIDE + prev] + em[s * TT + curr];
            } else {
                int t0_ = tg[0];
                acc += em[t0_] + trans[t0_ * TSTRIDE + TT];
            }
        }
    }
    #pragma unroll
    for (int off = 32; off; off >>= 1) acc += __shfl_xor(acc, off);
    if (j == 0) {
        int last = tg[len - 1];
        acc += trans[65 * TSTRIDE + last];
        diff_out[b] = zres - acc;
    }
}

__global__ __launch_bounds__(256) void crf_final_kernel(
    const float* __restrict__ diff,
    float* __restrict__ out)
{
    __shared__ float sdata[4];
    int t = threadIdx.x;
    float v = 0.f;
    for (int i = t; i < BB; i += 256) v += diff[i];
    #pragma unroll
    for (int off = 32; off; off >>= 1) v += __shfl_xor(v, off);
    if ((t & 63) == 0) sdata[t >> 6] = v;
    __syncthreads();
    if (t == 0) out[0] = (sdata[0] + sdata[1] + sdata[2] + sdata[3]) * (1.0f / BB);
}

extern "C" void kernel_launch(void* const* d_in, const int* in_sizes, int n_in,
                              void* d_out, int out_size, void* d_ws, size_t ws_size,
                              hipStream_t stream) {
    const float* emissions = (const float*)d_in[0];
    const int*   tags      = (const int*)d_in[1];
    const float* mask      = (const float*)d_in[2];
    const float* trans     = (const float*)d_in[3];
    float* out  = (float*)d_out;
    float* diff = (float*)d_ws;

    crf_fused_kernel<<<BB, 64, 0, stream>>>(emissions, tags, mask, trans, diff);
    crf_final_kernel<<<1, 256, 0, stream>>>(diff, out);
}